// Round 1
// baseline (3243.561 us; speedup 1.0000x reference)
//
#include <hip/hip_runtime.h>
#include <cstddef>

#define TE 64
#define NTHREADS 512

// LDS layout (float offsets)
#define SH_OFF    0        // 16384 floats: H/R tile [64][256]; first 8192 alias A tile [64][128]
#define SW_OFF    16384    // 8192 floats: W chunk [32][256]
#define SW2_OFF   24576    // 256 floats: [pw2 | vw2]
#define SLOSS_OFF 24832    // 64 floats
#define SROW_OFF  24896    // 64 ints
#define SCOL_OFF  24960    // 64 ints
#define SMEM_FLOATS 25024  // 100096 bytes

__global__ __launch_bounds__(NTHREADS)
void fused_edge_mlp(
    const float* __restrict__ x,
    const int*   __restrict__ edge_index,
    const float* __restrict__ gf,
    const int*   __restrict__ labels,
    const float* __restrict__ se_w1, const float* __restrict__ se_b1,
    const float* __restrict__ se_w2, const float* __restrict__ se_b2,
    const float* __restrict__ pw1,  const float* __restrict__ pb1,
    const float* __restrict__ pw2,  const float* __restrict__ pb2,
    const float* __restrict__ vw1,  const float* __restrict__ vb1,
    const float* __restrict__ vw2,  const float* __restrict__ vb2,
    float* __restrict__ out,        // out[0]=loss (finalize kernel), out[1..E]=actions
    float* __restrict__ ws_partial,
    int n_edges)
{
  extern __shared__ float smem[];
  float* sH    = smem + SH_OFF;
  float* sA    = smem + SH_OFF;     // alias: A tile only live during layer 1 k-loops
  float* sW    = smem + SW_OFF;
  float* sW2   = smem + SW2_OFF;
  float* sLoss = smem + SLOSS_OFF;
  int*   sRow  = (int*)(smem + SROW_OFF);
  int*   sCol  = (int*)(smem + SCOL_OFF);

  const int t  = threadIdx.x;
  const int e0 = blockIdx.x * TE;

  // thread mapping for [64 x 256] register tiles: 8 edges x 4 cols per thread
  const int tc  = t & 31;          // 32 col groups of 4 -> 128 cols
  const int teh = t >> 5;          // 0..15
  const int te  = teh & 7;         // edge group: edges te*8 .. te*8+7
  const int ch  = teh >> 3;        // column half (0: cols 0..127, 1: 128..255)
  const int colBase = ch * 128 + tc * 4;

  // ---- initial small loads ----
  if (t < 64) {
    int eg = e0 + t;
    sRow[t] = (eg < n_edges) ? edge_index[eg] : 0;
  } else if (t < 128) {
    int eg = e0 + (t - 64);
    sCol[t - 64] = (eg < n_edges) ? edge_index[(size_t)n_edges + eg] : 0;
  } else if (t < 384) {
    int c = t - 128;
    sW2[c] = (c < 128) ? pw2[c] : vw2[c - 128];
  }

  float acc[8][4];

  auto zero_acc = [&]() {
    #pragma unroll
    for (int i = 0; i < 8; ++i)
      #pragma unroll
      for (int j = 0; j < 4; ++j)
        acc[i][j] = 0.f;
  };

  // acc += A[64 x 32] (row stride LDA) @ sW[32][256], this thread's 8x4 sub-tile
  auto gemm_chunk = [&](const float* Ak, int LDA) {
    #pragma unroll
    for (int k4 = 0; k4 < 8; ++k4) {
      float a[8][4];
      #pragma unroll
      for (int i = 0; i < 8; ++i) {
        float4 v = *(const float4*)&Ak[(te * 8 + i) * LDA + k4 * 4];
        a[i][0] = v.x; a[i][1] = v.y; a[i][2] = v.z; a[i][3] = v.w;
      }
      #pragma unroll
      for (int dk = 0; dk < 4; ++dk) {
        float4 w = *(const float4*)&sW[(k4 * 4 + dk) * 256 + colBase];
        #pragma unroll
        for (int i = 0; i < 8; ++i) {
          acc[i][0] = fmaf(a[i][dk], w.x, acc[i][0]);
          acc[i][1] = fmaf(a[i][dk], w.y, acc[i][1]);
          acc[i][2] = fmaf(a[i][dk], w.z, acc[i][2]);
          acc[i][3] = fmaf(a[i][dk], w.w, acc[i][3]);
        }
      }
    }
  };

  // ================= Layer 1: H1 = relu(state @ se_w1 + b1), K = 3*128 =================
  zero_acc();
  for (int seg = 0; seg < 3; ++seg) {
    __syncthreads();  // indices ready (seg 0) / previous chunk's sA reads done
    {
      const float* src = (seg == 2) ? gf : x;
      const int*   idx = (seg == 0) ? sRow : sCol;
      #pragma unroll
      for (int j = 0; j < 4; ++j) {
        int i4  = t + j * NTHREADS;   // 0..2047
        int r   = i4 >> 5;            // 0..63
        int cf4 = i4 & 31;            // 0..31
        int node = idx[r];
        *(float4*)&sA[r * 128 + cf4 * 4] =
            *(const float4*)&src[(size_t)node * 128 + cf4 * 4];
      }
    }
    for (int kc = 0; kc < 4; ++kc) {
      if (kc > 0) __syncthreads();
      #pragma unroll
      for (int j = 0; j < 4; ++j) {
        int i4  = t + j * NTHREADS;
        int r   = i4 >> 6;            // 0..31
        int cf4 = i4 & 63;            // 0..63
        *(float4*)&sW[r * 256 + cf4 * 4] =
            *(const float4*)&se_w1[((size_t)(seg * 128 + kc * 32 + r)) * 256 + cf4 * 4];
      }
      __syncthreads();
      gemm_chunk(sA + kc * 32, 128);
    }
  }

  // epilogue: relu(+b1) -> sH (overwrites sA alias; sync first)
  __syncthreads();
  {
    float4 b = *(const float4*)&se_b1[colBase];
    #pragma unroll
    for (int i = 0; i < 8; ++i) {
      float4 hv;
      hv.x = fmaxf(acc[i][0] + b.x, 0.f);
      hv.y = fmaxf(acc[i][1] + b.y, 0.f);
      hv.z = fmaxf(acc[i][2] + b.z, 0.f);
      hv.w = fmaxf(acc[i][3] + b.w, 0.f);
      *(float4*)&sH[(te * 8 + i) * 256 + colBase] = hv;
    }
  }
  __syncthreads();

  // ================= Layer 2: H = H1 @ se_w2 + b2 (no relu), K = 256 =================
  zero_acc();
  for (int kc = 0; kc < 8; ++kc) {
    if (kc > 0) __syncthreads();
    #pragma unroll
    for (int j = 0; j < 4; ++j) {
      int i4  = t + j * NTHREADS;
      int r   = i4 >> 6;
      int cf4 = i4 & 63;
      *(float4*)&sW[r * 256 + cf4 * 4] =
          *(const float4*)&se_w2[((size_t)(kc * 32 + r)) * 256 + cf4 * 4];
    }
    __syncthreads();
    gemm_chunk(sH + kc * 32, 256);
  }

  __syncthreads();  // all H1 reads done before overwrite
  {
    float4 b = *(const float4*)&se_b2[colBase];
    #pragma unroll
    for (int i = 0; i < 8; ++i) {
      float4 hv;
      hv.x = acc[i][0] + b.x;
      hv.y = acc[i][1] + b.y;
      hv.z = acc[i][2] + b.z;
      hv.w = acc[i][3] + b.w;
      *(float4*)&sH[(te * 8 + i) * 256 + colBase] = hv;
    }
  }
  __syncthreads();

  // ============ Layer 3: R = relu(H @ [pw1|vw1] + [pb1|vb1]), K = 256, 256 cols ============
  zero_acc();
  for (int kc = 0; kc < 8; ++kc) {
    if (kc > 0) __syncthreads();
    #pragma unroll
    for (int j = 0; j < 4; ++j) {
      int i4  = t + j * NTHREADS;
      int r   = i4 >> 6;
      int cf4 = i4 & 63;
      int krow = kc * 32 + r;
      float4 wv;
      if (cf4 < 32) wv = *(const float4*)&pw1[(size_t)krow * 128 + cf4 * 4];
      else          wv = *(const float4*)&vw1[(size_t)krow * 128 + (cf4 - 32) * 4];
      *(float4*)&sW[r * 256 + cf4 * 4] = wv;
    }
    __syncthreads();
    gemm_chunk(sH + kc * 32, 256);
  }

  __syncthreads();  // all H reads done before overwrite
  {
    float4 b = (ch == 0) ? *(const float4*)&pb1[tc * 4] : *(const float4*)&vb1[tc * 4];
    #pragma unroll
    for (int i = 0; i < 8; ++i) {
      float4 hv;
      hv.x = fmaxf(acc[i][0] + b.x, 0.f);
      hv.y = fmaxf(acc[i][1] + b.y, 0.f);
      hv.z = fmaxf(acc[i][2] + b.z, 0.f);
      hv.w = fmaxf(acc[i][3] + b.w, 0.f);
      *(float4*)&sH[(te * 8 + i) * 256 + colBase] = hv;
    }
  }
  __syncthreads();

  // ================= Layer 4: heads (two 128-dots per edge) =================
  {
    int d    = t >> 2;     // 0..127
    int lk   = t & 3;      // k quarter
    int edge = d & 63;
    int head = d >> 6;     // 0: policy, 1: value
    int base = head * 128 + lk * 32;
    float p = 0.f;
    #pragma unroll
    for (int kk = 0; kk < 32; kk += 4) {
      float4 r4 = *(const float4*)&sH[edge * 256 + base + kk];
      float4 w4 = *(const float4*)&sW2[base + kk];
      p = fmaf(r4.x, w4.x, p);
      p = fmaf(r4.y, w4.y, p);
      p = fmaf(r4.z, w4.z, p);
      p = fmaf(r4.w, w4.w, p);
    }
    p += __shfl_xor(p, 1);
    p += __shfl_xor(p, 2);
    if (lk == 0) {
      int eg = e0 + edge;
      bool valid = eg < n_edges;
      if (head == 0) {
        float logit = p + pb2[0];
        if (valid) out[1 + eg] = (logit > 0.f) ? 1.f : 0.f;  // sigmoid(l)>0.5 <=> l>0
      } else {
        float term = 0.f;
        if (valid) {
          float z = p + vb2[0];
          float yv = (float)labels[sRow[edge]];
          term = fmaxf(z, 0.f) - z * yv + log1pf(expf(-fabsf(z)));
        }
        sLoss[edge] = term;
      }
    }
  }
  __syncthreads();
  if (t == 0) {
    float s = 0.f;
    #pragma unroll 4
    for (int i = 0; i < 64; ++i) s += sLoss[i];  // fixed order -> deterministic
    ws_partial[blockIdx.x] = s;
  }
}

__global__ void finalize_loss(const float* __restrict__ ws, float* __restrict__ out,
                              int n, double invE)
{
  __shared__ double sd[256];
  double a = 0.0;
  for (int i = threadIdx.x; i < n; i += 256) a += (double)ws[i];  // fixed order
  sd[threadIdx.x] = a;
  __syncthreads();
  for (int off = 128; off > 0; off >>= 1) {
    if ((int)threadIdx.x < off) sd[threadIdx.x] += sd[threadIdx.x + off];
    __syncthreads();
  }
  if (threadIdx.x == 0) out[0] = (float)(sd[0] * invE);
}

extern "C" void kernel_launch(void* const* d_in, const int* in_sizes, int n_in,
                              void* d_out, int out_size, void* d_ws, size_t ws_size,
                              hipStream_t stream) {
  const float* x      = (const float*)d_in[0];
  const int*   ei     = (const int*)  d_in[1];
  const float* gf     = (const float*)d_in[2];
  const int*   labels = (const int*)  d_in[3];
  const float* se_w1  = (const float*)d_in[4];
  const float* se_b1  = (const float*)d_in[5];
  const float* se_w2  = (const float*)d_in[6];
  const float* se_b2  = (const float*)d_in[7];
  const float* pw1    = (const float*)d_in[8];
  const float* pb1    = (const float*)d_in[9];
  const float* pw2    = (const float*)d_in[10];
  const float* pb2    = (const float*)d_in[11];
  const float* vw1    = (const float*)d_in[12];
  const float* vb1    = (const float*)d_in[13];
  const float* vw2    = (const float*)d_in[14];
  const float* vb2    = (const float*)d_in[15];

  int n_edges = in_sizes[1] / 2;
  int nblocks = (n_edges + TE - 1) / TE;
  float* out = (float*)d_out;
  float* ws  = (float*)d_ws;

  size_t shmem = SMEM_FLOATS * sizeof(float);  // ~100 KB
  // allow >64KB dynamic LDS (idempotent; harmless if already set / unsupported)
  (void)hipFuncSetAttribute((const void*)fused_edge_mlp,
                            hipFuncAttributeMaxDynamicSharedMemorySize, (int)shmem);

  fused_edge_mlp<<<dim3(nblocks), dim3(NTHREADS), shmem, stream>>>(
      x, ei, gf, labels,
      se_w1, se_b1, se_w2, se_b2,
      pw1, pb1, pw2, pb2,
      vw1, vb1, vw2, vb2,
      out, ws, n_edges);

  finalize_loss<<<dim3(1), dim3(256), 0, stream>>>(ws, out, nblocks, 1.0 / (double)n_edges);
}

// Round 2
// 2766.442 us; speedup vs baseline: 1.1725x; 1.1725x over previous
//
#include <hip/hip_runtime.h>
#include <cstddef>

#define TE 64
#define NTHREADS 512
#define WR 8   // W-chunk rows

// LDS layout (float offsets)
#define SH_OFF    0                    // 16384 floats: H/R tile [64][256]; first 8192 alias A tile [64][128]
#define SW_OFF    16384                // 2048 floats: W chunk [8][256]
#define SW2_OFF   (SW_OFF + 2048)      // 256 floats: [pw2 | vw2]
#define SLOSS_OFF (SW2_OFF + 256)      // 64 floats
#define SROW_OFF  (SLOSS_OFF + 64)     // 64 ints
#define SCOL_OFF  (SROW_OFF + 64)      // 64 ints
#define SMEM_FLOATS (SCOL_OFF + 64)    // 18880 floats = 75520 B -> 2 blocks/CU

__global__ __launch_bounds__(NTHREADS, 4)   // 4 waves/SIMD -> 2 blocks/CU, VGPR<=128
void fused_edge_mlp(
    const float* __restrict__ x,
    const int*   __restrict__ edge_index,
    const float* __restrict__ gf,
    const int*   __restrict__ labels,
    const float* __restrict__ se_w1, const float* __restrict__ se_b1,
    const float* __restrict__ se_w2, const float* __restrict__ se_b2,
    const float* __restrict__ pw1,  const float* __restrict__ pb1,
    const float* __restrict__ pw2,  const float* __restrict__ pb2,
    const float* __restrict__ vw1,  const float* __restrict__ vb1,
    const float* __restrict__ vw2,  const float* __restrict__ vb2,
    float* __restrict__ out,        // out[0]=loss (finalize kernel), out[1..E]=actions
    float* __restrict__ ws_partial,
    int n_edges)
{
  extern __shared__ float smem[];
  float* sH    = smem + SH_OFF;
  float* sA    = smem + SH_OFF;     // alias: A tile only live during layer-1 k-loops
  float* sW    = smem + SW_OFF;
  float* sW2   = smem + SW2_OFF;
  float* sLoss = smem + SLOSS_OFF;
  int*   sRow  = (int*)(smem + SROW_OFF);
  int*   sCol  = (int*)(smem + SCOL_OFF);

  const int t  = threadIdx.x;
  const int e0 = blockIdx.x * TE;

  // register-tile mapping: 8 edges x 4 cols per thread over the [64 x 256] tile
  const int tc  = t & 31;
  const int teh = t >> 5;
  const int te  = teh & 7;          // edge group: edges te*8 .. te*8+7
  const int ch  = teh >> 3;         // column half
  const int colBase = ch * 128 + tc * 4;

  // per-thread W-chunk slot: thread t stages float4 #t of the [8][256] chunk
  const int wr  = t >> 6;           // row 0..7 within chunk
  const int wc4 = t & 63;           // float4 col 0..63

  // ---- initial small loads ----
  if (t < 64) {
    int eg = e0 + t;
    sRow[t] = (eg < n_edges) ? edge_index[eg] : 0;
  } else if (t < 128) {
    int eg = e0 + (t - 64);
    sCol[t - 64] = (eg < n_edges) ? edge_index[(size_t)n_edges + eg] : 0;
  } else if (t < 384) {
    int c = t - 128;
    sW2[c] = (c < 128) ? pw2[c] : vw2[c - 128];
  }

  float acc[8][4];
  auto zero_acc = [&]() {
    #pragma unroll
    for (int i = 0; i < 8; ++i)
      #pragma unroll
      for (int j = 0; j < 4; ++j) acc[i][j] = 0.f;
  };

  // W-chunk prefetch loaders (one float4 per thread)
  auto loadW1 = [&](int c) -> float4 {
    return *(const float4*)&se_w1[((size_t)(c * WR + wr)) * 256 + wc4 * 4];
  };
  auto loadW2 = [&](int c) -> float4 {
    return *(const float4*)&se_w2[((size_t)(c * WR + wr)) * 256 + wc4 * 4];
  };
  auto loadW3 = [&](int c) -> float4 {
    int row = c * WR + wr;
    if (wc4 < 32) return *(const float4*)&pw1[(size_t)row * 128 + wc4 * 4];
    else          return *(const float4*)&vw1[(size_t)row * 128 + (wc4 - 32) * 4];
  };

  // acc += A[64 x 8] (row stride LDA) @ sW[8][256], this thread's 8x4 sub-tile
  auto gemm8 = [&](const float* Ak, const int LDA) {
    #pragma unroll
    for (int k4 = 0; k4 < 2; ++k4) {
      float a[8][4];
      #pragma unroll
      for (int i = 0; i < 8; ++i) {
        float4 v = *(const float4*)&Ak[(te * 8 + i) * LDA + k4 * 4];
        a[i][0] = v.x; a[i][1] = v.y; a[i][2] = v.z; a[i][3] = v.w;
      }
      #pragma unroll
      for (int dk = 0; dk < 4; ++dk) {
        float4 w = *(const float4*)&sW[(k4 * 4 + dk) * 256 + colBase];
        #pragma unroll
        for (int i = 0; i < 8; ++i) {
          acc[i][0] = fmaf(a[i][dk], w.x, acc[i][0]);
          acc[i][1] = fmaf(a[i][dk], w.y, acc[i][1]);
          acc[i][2] = fmaf(a[i][dk], w.z, acc[i][2]);
          acc[i][3] = fmaf(a[i][dk], w.w, acc[i][3]);
        }
      }
    }
  };

  // A-tile gather for layer-1 segment (x[row] / x[col] / gf[col])
  auto stageA = [&](int seg) {
    const float* src = (seg == 2) ? gf : x;
    const int*   idx = (seg == 0) ? sRow : sCol;
    float4 tmp[4];
    #pragma unroll
    for (int j = 0; j < 4; ++j) {
      int i4  = t + j * NTHREADS;   // 0..2047
      int r   = i4 >> 5;
      int cf4 = i4 & 31;
      tmp[j] = *(const float4*)&src[(size_t)idx[r] * 128 + cf4 * 4];
    }
    #pragma unroll
    for (int j = 0; j < 4; ++j) {
      int i4 = t + j * NTHREADS;
      *(float4*)&sA[i4 * 4] = tmp[j];
    }
  };

  float4 wv = loadW1(0);  // prologue prefetch

  // ================= Layer 1: H1 = relu(state @ se_w1 + b1), 48 chunks =================
  zero_acc();
  for (int c = 0; c < 48; ++c) {
    __syncthreads();                       // readers done with sW(c-1) / sA(prev seg)
    if ((c & 15) == 0) stageA(c >> 4);
    *(float4*)&sW[t * 4] = wv;             // write chunk c
    __syncthreads();                       // sW(c) + sA ready
    if (c < 47) wv = loadW1(c + 1); else wv = loadW2(0);   // prefetch under gemm
    gemm8(sA + (c & 15) * WR, 128);
  }

  __syncthreads();  // all sA reads done before overwrite
  {
    float4 b = *(const float4*)&se_b1[colBase];
    #pragma unroll
    for (int i = 0; i < 8; ++i) {
      float4 hv;
      hv.x = fmaxf(acc[i][0] + b.x, 0.f);
      hv.y = fmaxf(acc[i][1] + b.y, 0.f);
      hv.z = fmaxf(acc[i][2] + b.z, 0.f);
      hv.w = fmaxf(acc[i][3] + b.w, 0.f);
      *(float4*)&sH[(te * 8 + i) * 256 + colBase] = hv;
    }
  }

  // ================= Layer 2: H = H1 @ se_w2 + b2 (no relu), 32 chunks =================
  zero_acc();
  for (int c = 0; c < 32; ++c) {
    __syncthreads();                       // also covers epilogue-1 sH writes (c==0)
    *(float4*)&sW[t * 4] = wv;
    __syncthreads();
    if (c < 31) wv = loadW2(c + 1); else wv = loadW3(0);
    gemm8(sH + c * WR, 256);
  }

  __syncthreads();  // all H1 reads done before overwrite
  {
    float4 b = *(const float4*)&se_b2[colBase];
    #pragma unroll
    for (int i = 0; i < 8; ++i) {
      float4 hv;
      hv.x = acc[i][0] + b.x;
      hv.y = acc[i][1] + b.y;
      hv.z = acc[i][2] + b.z;
      hv.w = acc[i][3] + b.w;
      *(float4*)&sH[(te * 8 + i) * 256 + colBase] = hv;
    }
  }

  // ============ Layer 3: R = relu(H @ [pw1|vw1] + [pb1|vb1]), 32 chunks ============
  zero_acc();
  for (int c = 0; c < 32; ++c) {
    __syncthreads();
    *(float4*)&sW[t * 4] = wv;
    __syncthreads();
    if (c < 31) wv = loadW3(c + 1);
    gemm8(sH + c * WR, 256);
  }

  __syncthreads();  // all H reads done before overwrite
  {
    float4 b = (ch == 0) ? *(const float4*)&pb1[tc * 4] : *(const float4*)&vb1[tc * 4];
    #pragma unroll
    for (int i = 0; i < 8; ++i) {
      float4 hv;
      hv.x = fmaxf(acc[i][0] + b.x, 0.f);
      hv.y = fmaxf(acc[i][1] + b.y, 0.f);
      hv.z = fmaxf(acc[i][2] + b.z, 0.f);
      hv.w = fmaxf(acc[i][3] + b.w, 0.f);
      *(float4*)&sH[(te * 8 + i) * 256 + colBase] = hv;
    }
  }
  __syncthreads();

  // ================= Layer 4: heads (two 128-dots per edge) =================
  {
    int d    = t >> 2;     // 0..127
    int lk   = t & 3;      // k quarter
    int edge = d & 63;
    int head = d >> 6;     // 0: policy, 1: value
    int base = head * 128 + lk * 32;
    float p = 0.f;
    #pragma unroll
    for (int kk = 0; kk < 32; kk += 4) {
      float4 r4 = *(const float4*)&sH[edge * 256 + base + kk];
      float4 w4 = *(const float4*)&sW2[base + kk];
      p = fmaf(r4.x, w4.x, p);
      p = fmaf(r4.y, w4.y, p);
      p = fmaf(r4.z, w4.z, p);
      p = fmaf(r4.w, w4.w, p);
    }
    p += __shfl_xor(p, 1);
    p += __shfl_xor(p, 2);
    if (lk == 0) {
      int eg = e0 + edge;
      bool valid = eg < n_edges;
      if (head == 0) {
        float logit = p + pb2[0];
        if (valid) out[1 + eg] = (logit > 0.f) ? 1.f : 0.f;  // sigmoid(l)>0.5 <=> l>0
      } else {
        float term = 0.f;
        if (valid) {
          float z = p + vb2[0];
          float yv = (float)labels[sRow[edge]];
          term = fmaxf(z, 0.f) - z * yv + log1pf(expf(-fabsf(z)));
        }
        sLoss[edge] = term;
      }
    }
  }
  __syncthreads();
  if (t == 0) {
    float s = 0.f;
    #pragma unroll 4
    for (int i = 0; i < 64; ++i) s += sLoss[i];  // fixed order -> deterministic
    ws_partial[blockIdx.x] = s;
  }
}

__global__ void finalize_loss(const float* __restrict__ ws, float* __restrict__ out,
                              int n, double invE)
{
  __shared__ double sd[256];
  double a = 0.0;
  for (int i = threadIdx.x; i < n; i += 256) a += (double)ws[i];  // fixed order
  sd[threadIdx.x] = a;
  __syncthreads();
  for (int off = 128; off > 0; off >>= 1) {
    if ((int)threadIdx.x < off) sd[threadIdx.x] += sd[threadIdx.x + off];
    __syncthreads();
  }
  if (threadIdx.x == 0) out[0] = (float)(sd[0] * invE);
}

extern "C" void kernel_launch(void* const* d_in, const int* in_sizes, int n_in,
                              void* d_out, int out_size, void* d_ws, size_t ws_size,
                              hipStream_t stream) {
  const float* x      = (const float*)d_in[0];
  const int*   ei     = (const int*)  d_in[1];
  const float* gf     = (const float*)d_in[2];
  const int*   labels = (const int*)  d_in[3];
  const float* se_w1  = (const float*)d_in[4];
  const float* se_b1  = (const float*)d_in[5];
  const float* se_w2  = (const float*)d_in[6];
  const float* se_b2  = (const float*)d_in[7];
  const float* pw1    = (const float*)d_in[8];
  const float* pb1    = (const float*)d_in[9];
  const float* pw2    = (const float*)d_in[10];
  const float* pb2    = (const float*)d_in[11];
  const float* vw1    = (const float*)d_in[12];
  const float* vb1    = (const float*)d_in[13];
  const float* vw2    = (const float*)d_in[14];
  const float* vb2    = (const float*)d_in[15];

  int n_edges = in_sizes[1] / 2;
  int nblocks = (n_edges + TE - 1) / TE;
  float* out = (float*)d_out;
  float* ws  = (float*)d_ws;

  size_t shmem = SMEM_FLOATS * sizeof(float);  // 75520 B -> 2 blocks/CU
  (void)hipFuncSetAttribute((const void*)fused_edge_mlp,
                            hipFuncAttributeMaxDynamicSharedMemorySize, (int)shmem);

  fused_edge_mlp<<<dim3(nblocks), dim3(NTHREADS), shmem, stream>>>(
      x, ei, gf, labels,
      se_w1, se_b1, se_w2, se_b2,
      pw1, pb1, pw2, pb2,
      vw1, vb1, vw2, vb2,
      out, ws, n_edges);

  finalize_loss<<<dim3(1), dim3(256), 0, stream>>>(ws, out, nblocks, 1.0 / (double)n_edges);
}

// Round 3
// 2764.996 us; speedup vs baseline: 1.1731x; 1.0005x over previous
//
#include <hip/hip_runtime.h>
#include <cstddef>

#define TE 64
#define NTHREADS 512
#define WR 8   // W-chunk rows

// LDS layout (float offsets)
#define SH_OFF    0                    // 16384 floats: H/R tile [64][256]; first 8192 alias A tile [64][128]
#define SW_OFF    16384                // 2048 floats: W chunk [8][256]
#define SW2_OFF   (SW_OFF + 2048)      // 256 floats: [pw2 | vw2]
#define SLOSS_OFF (SW2_OFF + 256)      // 64 floats
#define SROW_OFF  (SLOSS_OFF + 64)     // 64 ints
#define SCOL_OFF  (SROW_OFF + 64)      // 64 ints
#define SMEM_FLOATS (SCOL_OFF + 64)    // 18880 floats = 75520 B -> 2 blocks/CU

// waves_per_eu(4): min 4 waves/SIMD -> VGPR cap 128 (no spill at ~90 natural);
// LDS 75.5KB keeps 2 blocks/CU. (launch_bounds 2nd arg capped VGPR at 64 -> 1GB spill traffic, r2)
__global__ __launch_bounds__(NTHREADS) __attribute__((amdgpu_waves_per_eu(4)))
void fused_edge_mlp(
    const float* __restrict__ x,
    const int*   __restrict__ edge_index,
    const float* __restrict__ gf,
    const int*   __restrict__ labels,
    const float* __restrict__ se_w1, const float* __restrict__ se_b1,
    const float* __restrict__ se_w2, const float* __restrict__ se_b2,
    const float* __restrict__ pw1,  const float* __restrict__ pb1,
    const float* __restrict__ pw2,  const float* __restrict__ pb2,
    const float* __restrict__ vw1,  const float* __restrict__ vb1,
    const float* __restrict__ vw2,  const float* __restrict__ vb2,
    float* __restrict__ out,        // out[0]=loss (finalize kernel), out[1..E]=actions
    float* __restrict__ ws_partial,
    int n_edges)
{
  extern __shared__ float smem[];
  float* sH    = smem + SH_OFF;
  float* sA    = smem + SH_OFF;     // alias: A tile only live during layer-1 k-loops
  float* sW    = smem + SW_OFF;
  float* sW2   = smem + SW2_OFF;
  float* sLoss = smem + SLOSS_OFF;
  int*   sRow  = (int*)(smem + SROW_OFF);
  int*   sCol  = (int*)(smem + SCOL_OFF);

  const int t  = threadIdx.x;
  const int e0 = blockIdx.x * TE;

  // register-tile mapping: 8 edges x 4 cols per thread over the [64 x 256] tile
  const int tc  = t & 31;
  const int teh = t >> 5;
  const int te  = teh & 7;          // edge group: edges te*8 .. te*8+7
  const int ch  = teh >> 3;         // column half
  const int colBase = ch * 128 + tc * 4;

  // per-thread W-chunk slot: thread t stages float4 #t of the [8][256] chunk
  const int wr  = t >> 6;           // row 0..7 within chunk
  const int wc4 = t & 63;           // float4 col 0..63

  // ---- initial small loads ----
  if (t < 64) {
    int eg = e0 + t;
    sRow[t] = (eg < n_edges) ? edge_index[eg] : 0;
  } else if (t < 128) {
    int eg = e0 + (t - 64);
    sCol[t - 64] = (eg < n_edges) ? edge_index[(size_t)n_edges + eg] : 0;
  } else if (t < 384) {
    int c = t - 128;
    sW2[c] = (c < 128) ? pw2[c] : vw2[c - 128];
  }

  float acc[8][4];
  auto zero_acc = [&]() {
    #pragma unroll
    for (int i = 0; i < 8; ++i)
      #pragma unroll
      for (int j = 0; j < 4; ++j) acc[i][j] = 0.f;
  };

  // W-chunk prefetch loaders (one float4 per thread)
  auto loadW1 = [&](int c) -> float4 {
    return *(const float4*)&se_w1[((size_t)(c * WR + wr)) * 256 + wc4 * 4];
  };
  auto loadW2 = [&](int c) -> float4 {
    return *(const float4*)&se_w2[((size_t)(c * WR + wr)) * 256 + wc4 * 4];
  };
  auto loadW3 = [&](int c) -> float4 {
    int row = c * WR + wr;
    if (wc4 < 32) return *(const float4*)&pw1[(size_t)row * 128 + wc4 * 4];
    else          return *(const float4*)&vw1[(size_t)row * 128 + (wc4 - 32) * 4];
  };

  // acc += A[64 x 8] (row stride LDA) @ sW[8][256], this thread's 8x4 sub-tile
  auto gemm8 = [&](const float* Ak, const int LDA) {
    #pragma unroll
    for (int k4 = 0; k4 < 2; ++k4) {
      float a[8][4];
      #pragma unroll
      for (int i = 0; i < 8; ++i) {
        float4 v = *(const float4*)&Ak[(te * 8 + i) * LDA + k4 * 4];
        a[i][0] = v.x; a[i][1] = v.y; a[i][2] = v.z; a[i][3] = v.w;
      }
      #pragma unroll
      for (int dk = 0; dk < 4; ++dk) {
        float4 w = *(const float4*)&sW[(k4 * 4 + dk) * 256 + colBase];
        #pragma unroll
        for (int i = 0; i < 8; ++i) {
          acc[i][0] = fmaf(a[i][dk], w.x, acc[i][0]);
          acc[i][1] = fmaf(a[i][dk], w.y, acc[i][1]);
          acc[i][2] = fmaf(a[i][dk], w.z, acc[i][2]);
          acc[i][3] = fmaf(a[i][dk], w.w, acc[i][3]);
        }
      }
    }
  };

  // A-tile gather for layer-1 segment (x[row] / x[col] / gf[col])
  auto stageA = [&](int seg) {
    const float* src = (seg == 2) ? gf : x;
    const int*   idx = (seg == 0) ? sRow : sCol;
    float4 tmp[4];
    #pragma unroll
    for (int j = 0; j < 4; ++j) {
      int i4  = t + j * NTHREADS;   // 0..2047
      int r   = i4 >> 5;
      int cf4 = i4 & 31;
      tmp[j] = *(const float4*)&src[(size_t)idx[r] * 128 + cf4 * 4];
    }
    #pragma unroll
    for (int j = 0; j < 4; ++j) {
      int i4 = t + j * NTHREADS;
      *(float4*)&sA[i4 * 4] = tmp[j];
    }
  };

  float4 wv = loadW1(0);  // prologue prefetch

  // ================= Layer 1: H1 = relu(state @ se_w1 + b1), 48 chunks =================
  zero_acc();
  for (int c = 0; c < 48; ++c) {
    __syncthreads();                       // readers done with sW(c-1) / sA(prev seg)
    if ((c & 15) == 0) stageA(c >> 4);
    *(float4*)&sW[t * 4] = wv;             // write chunk c
    __syncthreads();                       // sW(c) + sA ready
    if (c < 47) wv = loadW1(c + 1); else wv = loadW2(0);   // prefetch under gemm
    gemm8(sA + (c & 15) * WR, 128);
  }

  __syncthreads();  // all sA reads done before overwrite
  {
    float4 b = *(const float4*)&se_b1[colBase];
    #pragma unroll
    for (int i = 0; i < 8; ++i) {
      float4 hv;
      hv.x = fmaxf(acc[i][0] + b.x, 0.f);
      hv.y = fmaxf(acc[i][1] + b.y, 0.f);
      hv.z = fmaxf(acc[i][2] + b.z, 0.f);
      hv.w = fmaxf(acc[i][3] + b.w, 0.f);
      *(float4*)&sH[(te * 8 + i) * 256 + colBase] = hv;
    }
  }

  // ================= Layer 2: H = H1 @ se_w2 + b2 (no relu), 32 chunks =================
  zero_acc();
  for (int c = 0; c < 32; ++c) {
    __syncthreads();                       // also covers epilogue-1 sH writes (c==0)
    *(float4*)&sW[t * 4] = wv;
    __syncthreads();
    if (c < 31) wv = loadW2(c + 1); else wv = loadW3(0);
    gemm8(sH + c * WR, 256);
  }

  __syncthreads();  // all H1 reads done before overwrite
  {
    float4 b = *(const float4*)&se_b2[colBase];
    #pragma unroll
    for (int i = 0; i < 8; ++i) {
      float4 hv;
      hv.x = acc[i][0] + b.x;
      hv.y = acc[i][1] + b.y;
      hv.z = acc[i][2] + b.z;
      hv.w = acc[i][3] + b.w;
      *(float4*)&sH[(te * 8 + i) * 256 + colBase] = hv;
    }
  }

  // ============ Layer 3: R = relu(H @ [pw1|vw1] + [pb1|vb1]), 32 chunks ============
  zero_acc();
  for (int c = 0; c < 32; ++c) {
    __syncthreads();
    *(float4*)&sW[t * 4] = wv;
    __syncthreads();
    if (c < 31) wv = loadW3(c + 1);
    gemm8(sH + c * WR, 256);
  }

  __syncthreads();  // all H reads done before overwrite
  {
    float4 b = (ch == 0) ? *(const float4*)&pb1[tc * 4] : *(const float4*)&vb1[tc * 4];
    #pragma unroll
    for (int i = 0; i < 8; ++i) {
      float4 hv;
      hv.x = fmaxf(acc[i][0] + b.x, 0.f);
      hv.y = fmaxf(acc[i][1] + b.y, 0.f);
      hv.z = fmaxf(acc[i][2] + b.z, 0.f);
      hv.w = fmaxf(acc[i][3] + b.w, 0.f);
      *(float4*)&sH[(te * 8 + i) * 256 + colBase] = hv;
    }
  }
  __syncthreads();

  // ================= Layer 4: heads (two 128-dots per edge) =================
  {
    int d    = t >> 2;     // 0..127
    int lk   = t & 3;      // k quarter
    int edge = d & 63;
    int head = d >> 6;     // 0: policy, 1: value
    int base = head * 128 + lk * 32;
    float p = 0.f;
    #pragma unroll
    for (int kk = 0; kk < 32; kk += 4) {
      float4 r4 = *(const float4*)&sH[edge * 256 + base + kk];
      float4 w4 = *(const float4*)&sW2[base + kk];
      p = fmaf(r4.x, w4.x, p);
      p = fmaf(r4.y, w4.y, p);
      p = fmaf(r4.z, w4.z, p);
      p = fmaf(r4.w, w4.w, p);
    }
    p += __shfl_xor(p, 1);
    p += __shfl_xor(p, 2);
    if (lk == 0) {
      int eg = e0 + edge;
      bool valid = eg < n_edges;
      if (head == 0) {
        float logit = p + pb2[0];
        if (valid) out[1 + eg] = (logit > 0.f) ? 1.f : 0.f;  // sigmoid(l)>0.5 <=> l>0
      } else {
        float term = 0.f;
        if (valid) {
          float z = p + vb2[0];
          float yv = (float)labels[sRow[edge]];
          term = fmaxf(z, 0.f) - z * yv + log1pf(expf(-fabsf(z)));
        }
        sLoss[edge] = term;
      }
    }
  }
  __syncthreads();
  if (t == 0) {
    float s = 0.f;
    #pragma unroll 4
    for (int i = 0; i < 64; ++i) s += sLoss[i];  // fixed order -> deterministic
    ws_partial[blockIdx.x] = s;
  }
}

__global__ void finalize_loss(const float* __restrict__ ws, float* __restrict__ out,
                              int n, double invE)
{
  __shared__ double sd[256];
  double a = 0.0;
  for (int i = threadIdx.x; i < n; i += 256) a += (double)ws[i];  // fixed order
  sd[threadIdx.x] = a;
  __syncthreads();
  for (int off = 128; off > 0; off >>= 1) {
    if ((int)threadIdx.x < off) sd[threadIdx.x] += sd[threadIdx.x + off];
    __syncthreads();
  }
  if (threadIdx.x == 0) out[0] = (float)(sd[0] * invE);
}

extern "C" void kernel_launch(void* const* d_in, const int* in_sizes, int n_in,
                              void* d_out, int out_size, void* d_ws, size_t ws_size,
                              hipStream_t stream) {
  const float* x      = (const float*)d_in[0];
  const int*   ei     = (const int*)  d_in[1];
  const float* gf     = (const float*)d_in[2];
  const int*   labels = (const int*)  d_in[3];
  const float* se_w1  = (const float*)d_in[4];
  const float* se_b1  = (const float*)d_in[5];
  const float* se_w2  = (const float*)d_in[6];
  const float* se_b2  = (const float*)d_in[7];
  const float* pw1    = (const float*)d_in[8];
  const float* pb1    = (const float*)d_in[9];
  const float* pw2    = (const float*)d_in[10];
  const float* pb2    = (const float*)d_in[11];
  const float* vw1    = (const float*)d_in[12];
  const float* vb1    = (const float*)d_in[13];
  const float* vw2    = (const float*)d_in[14];
  const float* vb2    = (const float*)d_in[15];

  int n_edges = in_sizes[1] / 2;
  int nblocks = (n_edges + TE - 1) / TE;
  float* out = (float*)d_out;
  float* ws  = (float*)d_ws;

  size_t shmem = SMEM_FLOATS * sizeof(float);  // 75520 B -> 2 blocks/CU
  (void)hipFuncSetAttribute((const void*)fused_edge_mlp,
                            hipFuncAttributeMaxDynamicSharedMemorySize, (int)shmem);

  fused_edge_mlp<<<dim3(nblocks), dim3(NTHREADS), shmem, stream>>>(
      x, ei, gf, labels,
      se_w1, se_b1, se_w2, se_b2,
      pw1, pb1, pw2, pb2,
      vw1, vb1, vw2, vb2,
      out, ws, n_edges);

  finalize_loss<<<dim3(1), dim3(256), 0, stream>>>(ws, out, nblocks, 1.0 / (double)n_edges);
}